// Round 5
// baseline (305.600 us; speedup 1.0000x reference)
//
#include <hip/hip_runtime.h>

// Problem constants (from reference): S_SENT=256, L=128, D=768, C=21
#define NS 32768          // support tokens = 256*128
#define NQ 32768          // query tokens
#define DIM 768
#define NC 21

// Workspace layout (in floats)
#define WS_CS    0        // class_sum [21*768]
#define WS_CNT   16128    // counts    [21]
#define WS_PROTO 16384    // proto     [21*768]
#define WS_PNORM 32512    // pnorm     [21]
#define WS_ZERO_FLOATS 16384   // zero class_sum + counts region

// ---------------- Kernel 0: per-class masked counts ----------------
__global__ __launch_bounds__(256) void k_counts(const int* __restrict__ lab,
                                                const int* __restrict__ msk,
                                                float* __restrict__ ws) {
    __shared__ int cnt[NC];
    int tid = threadIdx.x;
    if (tid < NC) cnt[tid] = 0;
    __syncthreads();
    int idx = blockIdx.x * 256 + tid;
    int stride = gridDim.x * 256;
    for (int i = idx; i < NS; i += stride) {
        if (msk[i]) atomicAdd(&cnt[lab[i]], 1);
    }
    __syncthreads();
    if (tid < NC && cnt[tid] > 0) atomicAdd(&ws[WS_CNT + tid], (float)cnt[tid]);
}

// ---------------- Kernel 1: class sums (segment-sum) ----------------
// Each block: 256 tokens x 256 D-columns. Thread tid exclusively owns
// column (dbase + tid) -> race-free LDS accumulation, no atomics.
// LDS access acc[c][tid]: c wave-uniform, addresses consecutive -> no
// bank conflicts (2 lanes/bank is free).
#define K1_TOK 256
#define K1_DCOLS 256
__global__ __launch_bounds__(256) void k_classsum(const float* __restrict__ emb,
                                                  const int* __restrict__ lab,
                                                  const int* __restrict__ msk,
                                                  float* __restrict__ ws) {
    __shared__ float acc[NC][K1_DCOLS];   // 21.5 KB -> ~7 blocks/CU, 28 waves/CU
    int tid = threadIdx.x;
    for (int i = tid; i < NC * K1_DCOLS; i += 256) ((float*)acc)[i] = 0.f;
    __syncthreads();

    int chunk = blockIdx.x;           // token chunk [0,128)
    int dblk  = blockIdx.y;           // [0,3)
    int dbase = dblk * K1_DCOLS;
    int t0    = chunk * K1_TOK;
    const float* ebase = emb + (size_t)t0 * DIM + dbase;

    #pragma unroll 1
    for (int tt = 0; tt < K1_TOK; tt += 4) {
        // 4 tokens in flight (latency hiding)
        float v0 = ebase[(size_t)(tt + 0) * DIM + tid];
        float v1 = ebase[(size_t)(tt + 1) * DIM + tid];
        float v2 = ebase[(size_t)(tt + 2) * DIM + tid];
        float v3 = ebase[(size_t)(tt + 3) * DIM + tid];
        int t = t0 + tt;
        int c0 = lab[t + 0], m0 = msk[t + 0];
        int c1 = lab[t + 1], m1 = msk[t + 1];
        int c2 = lab[t + 2], m2 = msk[t + 2];
        int c3 = lab[t + 3], m3 = msk[t + 3];
        if (m0) acc[c0][tid] += v0;   // wave-uniform branch + class index
        if (m1) acc[c1][tid] += v1;
        if (m2) acc[c2][tid] += v2;
        if (m3) acc[c3][tid] += v3;
    }
    __syncthreads();

    // Flush: 21 coalesced atomic rounds per block
    #pragma unroll
    for (int c = 0; c < NC; ++c) {
        atomicAdd(&ws[WS_CS + c * DIM + dbase + tid], acc[c][tid]);
    }
}

// ---------------- Kernel 2: finalize proto + pnorm ----------------
__global__ __launch_bounds__(256) void k_proto(float* __restrict__ ws) {
    int c = blockIdx.x;
    int tid = threadIdx.x;
    float cnt = ws[WS_CNT + c];
    float scale = (cnt > 0.f) ? (1.f / cnt) : 0.f;
    float ssq = 0.f;
    for (int d = tid; d < DIM; d += 256) {
        float p = ws[WS_CS + c * DIM + d] * scale;
        ws[WS_PROTO + c * DIM + d] = p;
        ssq += p * p;
    }
    #pragma unroll
    for (int m = 32; m; m >>= 1) ssq += __shfl_xor(ssq, m);
    __shared__ float w4[4];
    if ((tid & 63) == 0) w4[tid >> 6] = ssq;
    __syncthreads();
    if (tid == 0) ws[WS_PNORM + c] = w4[0] + w4[1] + w4[2] + w4[3];
}

// ---------------- Kernel 3: logits + argmax ----------------
// One wave per query token. Lane holds 12 columns as 3x float4 (16B/lane
// coalesced). 6-step xor-butterfly per class dot; all lanes end with the
// full logit vector in registers (static indexing only).
__global__ __launch_bounds__(256) void k_logits(const float* __restrict__ qemb,
                                                const float* __restrict__ ws,
                                                float* __restrict__ out) {
    int wid  = threadIdx.x >> 6;
    int lane = threadIdx.x & 63;
    int q = blockIdx.x * 4 + wid;

    const float4* q4 = (const float4*)qemb + (size_t)q * (DIM / 4);
    float4 a = q4[lane], b = q4[lane + 64], c4 = q4[lane + 128];

    float qn = a.x * a.x + a.y * a.y + a.z * a.z + a.w * a.w
             + b.x * b.x + b.y * b.y + b.z * b.z + b.w * b.w
             + c4.x * c4.x + c4.y * c4.y + c4.z * c4.z + c4.w * c4.w;
    #pragma unroll
    for (int m = 32; m; m >>= 1) qn += __shfl_xor(qn, m);

    const float4* p4 = (const float4*)(ws + WS_PROTO);
    float logit[NC];
    #pragma unroll
    for (int c = 0; c < NC; ++c) {
        const float4* pr = p4 + c * (DIM / 4);
        float4 x = pr[lane], y = pr[lane + 64], z = pr[lane + 128];
        float d = a.x * x.x + a.y * x.y + a.z * x.z + a.w * x.w
                + b.x * y.x + b.y * y.y + b.z * y.z + b.w * y.w
                + c4.x * z.x + c4.y * z.y + c4.z * z.z + c4.w * z.w;
        #pragma unroll
        for (int m = 32; m; m >>= 1) d += __shfl_xor(d, m);
        logit[c] = 2.f * d - qn - ws[WS_PNORM + c];
    }

    // argmax (first max wins, matching jnp.argmax)
    float best = logit[0];
    int bi = 0;
    #pragma unroll
    for (int c = 1; c < NC; ++c) {
        if (logit[c] > best) { best = logit[c]; bi = c; }
    }

    // scatter: lane c writes logit[c] (select via cndmask chain, 1 store)
    float myv = 0.f;
    #pragma unroll
    for (int c = 0; c < NC; ++c) myv = (lane == c) ? logit[c] : myv;
    float* lrow = out + (size_t)q * NC;
    if (lane < NC) lrow[lane] = myv;
    if (lane == 0) out[(size_t)NQ * NC + q] = (float)bi;
}

extern "C" void kernel_launch(void* const* d_in, const int* in_sizes, int n_in,
                              void* d_out, int out_size, void* d_ws, size_t ws_size,
                              hipStream_t stream) {
    const float* semb = (const float*)d_in[0];
    const float* qemb = (const float*)d_in[1];
    const int*   lab  = (const int*)d_in[2];
    const int*   msk  = (const int*)d_in[3];
    float* ws  = (float*)d_ws;
    float* out = (float*)d_out;

    hipMemsetAsync(d_ws, 0, WS_ZERO_FLOATS * sizeof(float), stream);
    k_counts<<<64, 256, 0, stream>>>(lab, msk, ws);
    k_classsum<<<dim3(NS / K1_TOK, 3), 256, 0, stream>>>(semb, lab, msk, ws);
    k_proto<<<NC, 256, 0, stream>>>(ws);
    k_logits<<<NQ / 4, 256, 0, stream>>>(qemb, ws, out);
}